// Round 6
// baseline (30.272 us; speedup 1.0000x reference)
//
#include <hip/hip_runtime.h>
#include <math.h>
#include <stdint.h>

#define EPS 1e-12f

typedef __attribute__((ext_vector_type(8))) short short8v;   // 8 bf16, 4 VGPRs
typedef __attribute__((ext_vector_type(8))) unsigned short us8;
typedef __attribute__((ext_vector_type(4))) float f32x4;

__device__ __forceinline__ unsigned short f2bf(float f) {
  union { float f; uint32_t u; } c; c.f = f;
  uint32_t u = c.u;
  uint32_t r = (u + 0x7FFFu + ((u >> 16) & 1u)) >> 16;  // RNE
  return (unsigned short)r;
}

__device__ __forceinline__ void gl_lds16(const void* g, void* l) {
  __builtin_amdgcn_global_load_lds(
      (const __attribute__((address_space(1))) unsigned int*)g,
      (__attribute__((address_space(3))) unsigned int*)l, 16, 0, 0);
}

// ---------------------------------------------------------------------------
// Workspace: Wb [9][128][64] bf16 @ 0 (147456 B), c-chunks XOR-swizzled by v&7
// ---------------------------------------------------------------------------

__global__ __launch_bounds__(256) void prep_wb(
    const float* __restrict__ w, const float* __restrict__ q,
    unsigned short* __restrict__ Wb) {
  int tid = threadIdx.x;
  int v = blockIdx.x * 4 + (tid >> 6);
  int c = tid & 63;
  float qn = q[0] * 0.01f;
  float scale = qn * qn;
  const float* wp = w + (v * 64 + c) * 9;
  float vals[9];
  float ss = 0.f;
#pragma unroll
  for (int j = 0; j < 9; ++j) { vals[j] = wp[j]; ss += vals[j] * vals[j]; }
#pragma unroll
  for (int off = 32; off > 0; off >>= 1) ss += __shfl_xor(ss, off);
  float inv = 1.0f / (sqrtf(ss + EPS) + scale);
  int pos = (((c >> 3) ^ (v & 7)) << 3) | (c & 7);
#pragma unroll
  for (int j = 0; j < 9; ++j) Wb[(j * 128 + v) * 64 + pos] = f2bf(vals[j] * inv);
}

// Fused conv: 512 blocks x 256 thr (4 waves), 2 blocks/CU.
// Tile = 2 h-rows x 64 w x 128 v. Async-dbuf weights, 1 barrier per l.
__global__ __launch_bounds__(256, 2) void conv_fused(
    const float* __restrict__ x, const unsigned short* __restrict__ Wb,
    const float* __restrict__ p, const float* __restrict__ q,
    float* __restrict__ out) {
  __shared__ unsigned short xs[4 * 66 * 64];  // [row][w+1][c] 33792 B, padded w
  __shared__ unsigned short wl[2 * 128 * 64]; // dbuf weight tiles, 32768 B
  __shared__ float sf[4 * 64];                // channel sq-sums of staged rows
  __shared__ float xiv[2 * 64];               // 1/(sqrt(box3x3)+scale)

  int b = blockIdx.x;              // 512 = 16 n x 32 row-pairs
  int n = b >> 5, hg = b & 31;
  int h0 = hg * 2;
  int tid = threadIdx.x;
  int lane = tid & 63, wid = tid >> 6;
  int wv = wid & 1, wp = wid >> 1;     // v-half, output row
  int lp = lane & 15, lg = lane >> 4;

  // async-stage weight tile l into LDS buffer bufi (4 KB per wave)
  auto stage_w = [&](int bufi, int l) {
    const unsigned short* src = Wb + l * 8192 + wid * 2048;
    unsigned short* dst = wl + bufi * 8192 + wid * 2048;
#pragma unroll
    for (int i = 0; i < 4; ++i)
      gl_lds16(src + i * 512 + lane * 8, dst + i * 512);
  };
  stage_w(0, 0);

  // ---- stage x rows h0-1 .. h0+2 (one row per wave), fp32->bf16 + sq-sum ----
  {
    int hh = h0 - 1 + wid;
    int w = lane;
    unsigned short* xrow = xs + wid * 4224 + (w + 1) * 64;
    if ((unsigned)hh < 64u) {
      const float* xp = x + ((size_t)n << 18) + hh * 64 + w;
      float ss = 0.f;
#pragma unroll
      for (int j = 0; j < 8; ++j) {                 // c-chunk j: c = 8j..8j+7
        float v[8];
#pragma unroll
        for (int e = 0; e < 8; ++e) v[e] = xp[(j * 8 + e) * 4096];
        us8 pk;
#pragma unroll
        for (int e = 0; e < 8; ++e) { ss += v[e] * v[e]; pk[e] = f2bf(v[e]); }
        *(us8*)(xrow + ((j ^ (w & 7)) * 8)) = pk;   // swizzled by logical w
      }
      sf[wid * 64 + w] = ss;
    } else {
      us8 z = {};
#pragma unroll
      for (int j = 0; j < 8; ++j) *(us8*)(xrow + j * 8) = z;
      sf[wid * 64 + w] = 0.f;
    }
  }
  // zero-pad columns w=-1 and w=64 for the 4 staged rows (64 writes)
  if (tid < 64) {
    int row = tid >> 4, side = (tid >> 3) & 1, j = tid & 7;
    us8 z = {};
    *(us8*)(xs + row * 4224 + (side ? 65 : 0) * 64 + j * 8) = z;
  }
  __syncthreads();   // xs, sf, wl(l=0) ready (vmcnt drained)

  // ---- xiv for the 2 output rows (ordered vs epilogue by loop barriers) ----
  if (tid < 128) {
    int r = tid >> 6, w = tid & 63;
    float qn = q[0] * 0.01f;
    float scale = qn * qn;
    float a = 0.f;
#pragma unroll
    for (int dr = 0; dr < 3; ++dr) {
      const float* base = sf + (r + dr) * 64;
      a += base[w];
      if (w > 0) a += base[w - 1];
      if (w < 63) a += base[w + 1];
    }
    xiv[r * 64 + w] = 1.0f / (sqrtf(a + EPS) + scale);
  }

  f32x4 acc[4][4];   // [pg][vg]
#pragma unroll
  for (int i = 0; i < 4; ++i)
#pragma unroll
    for (int j = 0; j < 4; ++j) acc[i][j] = (f32x4){0.f, 0.f, 0.f, 0.f};

  int buf = 0;
#pragma unroll
  for (int l = 0; l < 9; ++l) {
    if (l < 8) stage_w(buf ^ 1, l + 1);   // async prefetch next l
    const int a = l / 3, bs = l % 3;
    const unsigned short* xrow = xs + (wp + a) * 4224;
    const unsigned short* wbase = wl + buf * 8192 + wv * 4096;
#pragma unroll
    for (int half = 0; half < 2; ++half) {
      const int cbase = half * 4;
      short8v av[4], bv[4];
#pragma unroll
      for (int vg = 0; vg < 4; ++vg)
        av[vg] = *(const short8v*)(wbase + (vg * 16 + lp) * 64 +
                                   ((cbase + lg) ^ (lp & 7)) * 8);
#pragma unroll
      for (int pg = 0; pg < 4; ++pg) {
        int wx = pg * 16 + lp + bs - 1;          // -1..64; pad cols are zero
        bv[pg] = *(const short8v*)(xrow + (wx + 1) * 64 +
                                   ((cbase + lg) ^ (wx & 7)) * 8);
      }
#pragma unroll
      for (int pg = 0; pg < 4; ++pg)
#pragma unroll
        for (int vg = 0; vg < 4; ++vg)
          acc[pg][vg] = __builtin_amdgcn_mfma_f32_16x16x32_bf16(
              bv[pg], av[vg], acc[pg][vg], 0, 0, 0);
    }
    if (l < 8) {
      __syncthreads();   // drains gl_lds (vmcnt) + everyone done reading buf
      buf ^= 1;
    }
  }

  // ---- epilogue: D[pixel][v]; lane: w4 = pg*16+lg*4, v = wv*64+vg*16+lp ----
  int h = h0 + wp;
#pragma unroll
  for (int vg = 0; vg < 4; ++vg) {
    int v = wv * 64 + vg * 16 + lp;
    float t0 = p[v] * 0.1f;
    float e = t0 * t0;
    float* ob = out + ((size_t)(n * 128 + v)) * 4096 + h * 64;
#pragma unroll
    for (int pg = 0; pg < 4; ++pg) {
      int w4 = pg * 16 + lg * 4;
      float4 xv = *(const float4*)&xiv[wp * 64 + w4];
      float yv[4] = {acc[pg][vg][0] * xv.x, acc[pg][vg][1] * xv.y,
                     acc[pg][vg][2] * xv.z, acc[pg][vg][3] * xv.w};
      f32x4 o;
#pragma unroll
      for (int r = 0; r < 4; ++r) {
        float y = yv[r];
        float t = fabsf(y) + EPS;
        float rv = exp2f(e * log2f(t));
        o[r] = (y == 0.0f) ? 0.0f : copysignf(rv, y);
      }
      // nontemporal: keep the 32 MB output stream from evicting Wb in L2
      __builtin_nontemporal_store(o, (f32x4*)(ob + w4));
    }
  }
}

extern "C" void kernel_launch(void* const* d_in, const int* in_sizes, int n_in,
                              void* d_out, int out_size, void* d_ws, size_t ws_size,
                              hipStream_t stream) {
  const float* x = (const float*)d_in[0];   // [16,64,64,64]
  const float* w = (const float*)d_in[1];   // [128,64,9]
  const float* p = (const float*)d_in[2];   // [128]
  const float* q = (const float*)d_in[3];   // [1]
  float* out = (float*)d_out;               // [16,128,64,64]

  unsigned short* Wb = (unsigned short*)d_ws;

  prep_wb<<<32, 256, 0, stream>>>(w, q, Wb);
  conv_fused<<<512, 256, 0, stream>>>(x, Wb, p, q, out);
}